// Round 1
// baseline (124.627 us; speedup 1.0000x reference)
//
#include <hip/hip_runtime.h>
#include <hip/hip_fp16.h>

typedef _Float16 half8  __attribute__((ext_vector_type(8)));
typedef _Float16 half4v __attribute__((ext_vector_type(4)));
typedef float    f32x4  __attribute__((ext_vector_type(4)));

#define MFMA_F16 __builtin_amdgcn_mfma_f32_16x16x32_f16

// ---------------- kernel 0: W_q|W_k|W_v f32 -> concat f16 [384][1024] ----------------
__global__ __launch_bounds__(256) void wconv_k(const float* __restrict__ wq,
                                               const float* __restrict__ wk,
                                               const float* __restrict__ wv,
                                               _Float16* __restrict__ wh) {
    int i = (blockIdx.x * 256 + threadIdx.x) * 8;   // 393216 total elems
    const float* src; int off;
    if (i < 131072)      { src = wq; off = i; }
    else if (i < 262144) { src = wk; off = i - 131072; }
    else                 { src = wv; off = i - 262144; }
    float4 a = *(const float4*)(src + off);
    float4 b = *(const float4*)(src + off + 4);
    half8 h;
    h[0]=(_Float16)a.x; h[1]=(_Float16)a.y; h[2]=(_Float16)a.z; h[3]=(_Float16)a.w;
    h[4]=(_Float16)b.x; h[5]=(_Float16)b.y; h[6]=(_Float16)b.z; h[7]=(_Float16)b.w;
    *(half8*)(wh + i) = h;
}

// ---------------- kernel 1: fused QKV projection ----------------
// x [16384][1024] f32 -> Qh [16384][128] f16, Kh [16384][128] f16, Vth [8][128][2048] f16
// 256 blocks x 512 threads (8 waves). Block: 64 rows x 384 cols. Wave w: cols [48w,48w+48).
__global__ __launch_bounds__(512) void qkv_k(const float* __restrict__ x,
                                             const _Float16* __restrict__ wh,
                                             _Float16* __restrict__ qh,
                                             _Float16* __restrict__ kh,
                                             _Float16* __restrict__ vth) {
    __shared__ _Float16 xs[64 * 40];   // 64 rows x 32 k, padded to 40 (2-way bank alias = free)
    int tid = threadIdx.x;
    int w = tid >> 6, l = tid & 63;
    int fr = l & 15, fq = l >> 4;
    int row0 = blockIdx.x * 64;
    int ng0 = w * 48;

    f32x4 acc[4][3] = {};

    int srow = tid >> 3, sk4 = (tid & 7) * 4;
    const float* xg = x + (row0 + srow) * 1024 + sk4;
    _Float16* xw = &xs[srow * 40 + sk4];

    for (int kk = 0; kk < 32; ++kk) {
        float4 xa = *(const float4*)(xg + kk * 32);
        half4v hv;
        hv[0]=(_Float16)xa.x; hv[1]=(_Float16)xa.y; hv[2]=(_Float16)xa.z; hv[3]=(_Float16)xa.w;
        *(half4v*)xw = hv;
        __syncthreads();
        half8 wf[3], af[4];
#pragma unroll
        for (int f = 0; f < 3; ++f)
            wf[f] = *(const half8*)(wh + (ng0 + f * 16 + fr) * 1024 + kk * 32 + fq * 8);
#pragma unroll
        for (int mf = 0; mf < 4; ++mf)
            af[mf] = *(const half8*)(&xs[(mf * 16 + fr) * 40 + fq * 8]);
#pragma unroll
        for (int mf = 0; mf < 4; ++mf)
#pragma unroll
            for (int f = 0; f < 3; ++f)
                acc[mf][f] = MFMA_F16(af[mf], wf[f], acc[mf][f], 0, 0, 0);
        __syncthreads();
    }

    // epilogue: C row = row0 + mf*16 + fq*4 + r, col = ng0 + f*16 + fr
#pragma unroll
    for (int f = 0; f < 3; ++f) {
        int n0 = ng0 + f * 16 + fr;
#pragma unroll
        for (int mf = 0; mf < 4; ++mf) {
#pragma unroll
            for (int r = 0; r < 4; ++r) {
                int m = row0 + mf * 16 + fq * 4 + r;
                _Float16 v = (_Float16)acc[mf][f][r];
                if (n0 < 128)       qh[m * 128 + n0] = v;
                else if (n0 < 256)  kh[m * 128 + (n0 - 128)] = v;
                else                vth[(((m >> 11) << 7) + (n0 - 256)) * 2048 + (m & 2047)] = v;
            }
        }
    }
}

// ---------------- kernel 2: causal flash attention ----------------
// 256 blocks x 256 threads (4 waves). Block = (batch b = bid&7, q-tile qt = bid>>3, 64 rows).
// Wave w owns q rows [qt*64 + 16w, +16). kv tiles of 64, j = 0..qt.
__global__ __launch_bounds__(256) void attn_k(const _Float16* __restrict__ qh,
                                              const _Float16* __restrict__ kh,
                                              const _Float16* __restrict__ vth,
                                              float* __restrict__ out) {
    __shared__ _Float16 ks[64 * 136];   // K tile [64 kv][128 d], padded
    __shared__ _Float16 vs[128 * 72];   // Vt tile [128 d][64 kv], padded
    __shared__ _Float16 ps[64 * 72];    // P [4 waves][16 q][64 kv], padded

    int bid = blockIdx.x;
    int b = bid & 7, qt = bid >> 3;
    int tid = threadIdx.x, w = tid >> 6, l = tid & 63;
    int fr = l & 15, fq = l >> 4;

    // Q fragments, register-resident for the whole block
    half8 qf[4];
    const _Float16* qp = qh + ((b * 2048 + qt * 64 + w * 16 + fr) << 7);
#pragma unroll
    for (int c = 0; c < 4; ++c) qf[c] = *(const half8*)(qp + c * 32 + fq * 8);

    f32x4 acc[8] = {};
    float mrow[4], lrow[4];
#pragma unroll
    for (int r = 0; r < 4; ++r) { mrow[r] = -1e30f; lrow[r] = 0.0f; }

    for (int j = 0; j <= qt; ++j) {
        // stage K and Vt tiles (16 KB each) with 256 threads
#pragma unroll
        for (int u = 0; u < 4; ++u) {
            int ci = tid + u * 256;
            int kr = ci >> 4, c16 = ci & 15;
            uint4 kd = *(const uint4*)(kh + (((b << 11) + (j << 6) + kr) << 7) + c16 * 8);
            *(uint4*)(&ks[kr * 136 + c16 * 8]) = kd;
            int vd = ci >> 3, c8 = ci & 7;
            uint4 vv = *(const uint4*)(vth + ((((b << 7) + vd) << 11) + (j << 6) + c8 * 8));
            *(uint4*)(&vs[vd * 72 + c8 * 8]) = vv;
        }
        __syncthreads();

        // S = Q K^T (f32 accum); D layout: col = fr (kv), row = fq*4+r (q)
        f32x4 s[4] = {};
#pragma unroll
        for (int n = 0; n < 4; ++n) {
#pragma unroll
            for (int c = 0; c < 4; ++c) {
                half8 kf = *(const half8*)(&ks[(n * 16 + fr) * 136 + c * 32 + fq * 8]);
                s[n] = MFMA_F16(qf[c], kf, s[n], 0, 0, 0);
            }
        }
        const float sc = 0.088388347648318447f;  // 1/sqrt(128)
        if (j == qt) {
#pragma unroll
            for (int n = 0; n < 4; ++n)
#pragma unroll
                for (int r = 0; r < 4; ++r) {
                    int qrow = w * 16 + fq * 4 + r;
                    int kcol = n * 16 + fr;
                    float v = s[n][r] * sc;
                    s[n][r] = (kcol > qrow) ? -1e30f : v;
                }
        } else {
#pragma unroll
            for (int n = 0; n < 4; ++n)
#pragma unroll
                for (int r = 0; r < 4; ++r) s[n][r] *= sc;
        }

        // online softmax: row stats live in 16-lane groups
        float mx[4];
#pragma unroll
        for (int r = 0; r < 4; ++r)
            mx[r] = fmaxf(fmaxf(s[0][r], s[1][r]), fmaxf(s[2][r], s[3][r]));
#pragma unroll
        for (int off = 1; off < 16; off <<= 1)
#pragma unroll
            for (int r = 0; r < 4; ++r) mx[r] = fmaxf(mx[r], __shfl_xor(mx[r], off));
        float al[4];
#pragma unroll
        for (int r = 0; r < 4; ++r) {
            float nm = fmaxf(mrow[r], mx[r]);
            al[r] = __expf(mrow[r] - nm);
            mrow[r] = nm;
        }
        float rs[4] = {0.f, 0.f, 0.f, 0.f};
#pragma unroll
        for (int n = 0; n < 4; ++n)
#pragma unroll
            for (int r = 0; r < 4; ++r) {
                float p = __expf(s[n][r] - mrow[r]);
                s[n][r] = p;
                rs[r] += p;
            }
#pragma unroll
        for (int off = 1; off < 16; off <<= 1)
#pragma unroll
            for (int r = 0; r < 4; ++r) rs[r] += __shfl_xor(rs[r], off);
#pragma unroll
        for (int r = 0; r < 4; ++r) lrow[r] = lrow[r] * al[r] + rs[r];
#pragma unroll
        for (int dt = 0; dt < 8; ++dt)
#pragma unroll
            for (int r = 0; r < 4; ++r) acc[dt][r] *= al[r];

        // P -> LDS (per-wave region), then PV
#pragma unroll
        for (int n = 0; n < 4; ++n)
#pragma unroll
            for (int r = 0; r < 4; ++r)
                ps[(w * 16 + fq * 4 + r) * 72 + n * 16 + fr] = (_Float16)s[n][r];

        half8 pa[2];
#pragma unroll
        for (int c2 = 0; c2 < 2; ++c2)
            pa[c2] = *(const half8*)(&ps[(w * 16 + fr) * 72 + c2 * 32 + fq * 8]);
#pragma unroll
        for (int dt = 0; dt < 8; ++dt)
#pragma unroll
            for (int c2 = 0; c2 < 2; ++c2) {
                half8 vf = *(const half8*)(&vs[(dt * 16 + fr) * 72 + c2 * 32 + fq * 8]);
                acc[dt] = MFMA_F16(pa[c2], vf, acc[dt], 0, 0, 0);
            }
        __syncthreads();
    }

    float inv[4];
#pragma unroll
    for (int r = 0; r < 4; ++r) inv[r] = 1.0f / lrow[r];
    float* op = out + ((b * 2048 + qt * 64 + w * 16 + fq * 4) << 7) + fr;
#pragma unroll
    for (int dt = 0; dt < 8; ++dt)
#pragma unroll
        for (int r = 0; r < 4; ++r)
            op[r * 128 + dt * 16] = acc[dt][r] * inv[r];
}

extern "C" void kernel_launch(void* const* d_in, const int* in_sizes, int n_in,
                              void* d_out, int out_size, void* d_ws, size_t ws_size,
                              hipStream_t stream) {
    const float* x  = (const float*)d_in[0];
    const float* wq = (const float*)d_in[1];
    const float* wk = (const float*)d_in[2];
    const float* wv = (const float*)d_in[3];

    char* ws = (char*)d_ws;
    _Float16* wh  = (_Float16*)ws;                          // 768 KB
    _Float16* qhp = (_Float16*)(ws + (1u << 20));           // 4 MB
    _Float16* khp = (_Float16*)(ws + (1u << 20) + (4u << 20));
    _Float16* vtp = (_Float16*)(ws + (1u << 20) + (8u << 20));

    wconv_k<<<192, 256, 0, stream>>>(wq, wk, wv, wh);
    qkv_k<<<256, 512, 0, stream>>>(x, wh, qhp, khp, vtp);
    attn_k<<<256, 256, 0, stream>>>(qhp, khp, vtp, (float*)d_out);
}